// Round 2
// baseline (647.876 us; speedup 1.0000x reference)
//
#include <hip/hip_runtime.h>

// FocusOther: pixel-unshuffle (space-to-depth).
// in : [B=32, C=3, H=1024, W=1024] fp32
// out: [B, 4*C=12, H/2=512, W/2=512] fp32, channel order:
//   q=0: even rows, even cols
//   q=1: odd  rows, even cols
//   q=2: even rows, odd  cols
//   q=3: odd  rows, odd  cols
// out[b][q*3+c][h][w] = in[b][c][2h + (q&1)][2w + (q>>1)]
//
// Strategy: thread reads 8 consecutive input floats (2x float4, 32B),
// writes one float4 to the even-col quadrant (pr) and one float4 to the
// odd-col quadrant (pr+2). Per 64-lane wave: 2 KiB contiguous read,
// 2x 1 KiB contiguous writes — fully coalesced both sides.

#define W_IN   1024
#define H_IN   1024
#define W8     (W_IN / 8)       // 128 groups of 8 floats per input row

__global__ __launch_bounds__(256) void focus_kernel(
    const float* __restrict__ in, float* __restrict__ out, int total_f8) {
    int stride = gridDim.x * blockDim.x;
    for (int t = blockIdx.x * blockDim.x + threadIdx.x; t < total_f8; t += stride) {
        const float4* p = reinterpret_cast<const float4*>(in) + 2 * t;
        float4 v0 = p[0];
        float4 v1 = p[1];

        int f8   = t & (W8 - 1);        // 8-float group index within row
        int rowg = t >> 7;              // global input row (img*1024 + r)
        int r    = rowg & (H_IN - 1);   // row within image
        int img  = rowg >> 10;          // b*3 + c
        int b    = img / 3;             // magic-mul via compiler
        int c    = img - 3 * b;

        int pr = r & 1;                 // row parity -> quadrant 0/1 (even cols)
        int h  = r >> 1;                // output row
        int wo = f8 << 2;               // output col = 4*f8

        // out channel (even-col quadrant): b*12 + pr*3 + c; HW = 512*512 = 1<<18
        int base_even = ((b * 12 + pr * 3 + c) << 18) + (h << 9) + wo;
        int base_odd  = base_even + (6 << 18);  // quadrant q -> q+2: +6 channels

        *reinterpret_cast<float4*>(out + base_even) =
            make_float4(v0.x, v0.z, v1.x, v1.z);
        *reinterpret_cast<float4*>(out + base_odd) =
            make_float4(v0.y, v0.w, v1.y, v1.w);
    }
}

extern "C" void kernel_launch(void* const* d_in, const int* in_sizes, int n_in,
                              void* d_out, int out_size, void* d_ws, size_t ws_size,
                              hipStream_t stream) {
    const float* in = (const float*)d_in[0];
    float* out = (float*)d_out;
    int total_f8 = in_sizes[0] / 8;  // 12,582,912

    // Memory-bound streaming: cap grid at ~8 blocks/CU, grid-stride the rest.
    int block = 256;
    int grid = 2048;
    focus_kernel<<<grid, block, 0, stream>>>(in, out, total_f8);
}